// Round 1
// baseline (243.965 us; speedup 1.0000x reference)
//
#include <hip/hip_runtime.h>

typedef __bf16 bf16;
typedef bf16 bf16x8 __attribute__((ext_vector_type(8)));
typedef bf16 bf16x4 __attribute__((ext_vector_type(4)));
typedef float f32x4 __attribute__((ext_vector_type(4)));

#define MFMA16(a, b, c) __builtin_amdgcn_mfma_f32_16x16x32_bf16(a, b, c, 0, 0, 0)

// ---------------- merged prep kernel ----------------
// blocks [0,8192):      x fp32 -> bf16 (4 el/thread)
// blocks [8192,9216):   W transposes (Wq | Wkv | Wo) fp32[r][c] -> bf16[c][r]
// blocks [9216,10240):  sr_w [o][i][p] -> srwT [o][p*256+i] (4 el/thread)
__global__ void k_prep(const float* __restrict__ x, const float* __restrict__ Wq,
                       const float* __restrict__ Wkv, const float* __restrict__ Wo,
                       const float* __restrict__ srw,
                       bf16* __restrict__ x_bf, bf16* __restrict__ WqT,
                       bf16* __restrict__ WkvT, bf16* __restrict__ WoT,
                       bf16* __restrict__ srwT) {
  int bid = blockIdx.x, tid = threadIdx.x;
  if (bid < 8192) {
    int i = (bid * 256 + tid) * 4;
    float4 v = *(const float4*)(x + i);
    bf16x4 o;
    o[0] = (bf16)v.x; o[1] = (bf16)v.y; o[2] = (bf16)v.z; o[3] = (bf16)v.w;
    *(bf16x4*)(x_bf + i) = o;
  } else if (bid < 9216) {
    int id = (bid - 8192) * 256 + tid;  // 0..262143
    if (id < 65536) {                   // WqT
      int c = id >> 8, r = id & 255;
      WqT[id] = (bf16)Wq[r * 256 + c];
    } else if (id < 196608) {           // WkvT
      int l = id - 65536;
      int c = l >> 8, r = l & 255;      // c in 0..511
      WkvT[l] = (bf16)Wkv[r * 512 + c];
    } else {                            // WoT
      int l = id - 196608;
      int c = l >> 8, r = l & 255;
      WoT[l] = (bf16)Wo[r * 256 + c];
    }
  } else {
    int id4 = ((bid - 9216) * 256 + tid) * 4;  // input-linear o*4096+i*16+p
    int o = id4 >> 12, rem = id4 & 4095;
    int i = rem >> 4, p = rem & 15;            // p in {0,4,8,12}
    float4 v = *(const float4*)(srw + id4);
    srwT[(o << 12) + ((p + 0) << 8) + i] = (bf16)v.x;
    srwT[(o << 12) + ((p + 1) << 8) + i] = (bf16)v.y;
    srwT[(o << 12) + ((p + 2) << 8) + i] = (bf16)v.z;
    srwT[(o << 12) + ((p + 3) << 8) + i] = (bf16)v.w;
  }
}

// ---------------- generic MFMA GEMM ----------------
// C[M][N] = A[M][K] @ Bt[N][K]^T   (bf16 inputs, fp32 accum)
// AMODE 0: A row-major [M][K]
// AMODE 1: conv im2col gather from x_bf [B*4096][256]; K index = p*256 + i
// EMODE 2: KV scatter: K -> [bh][key][d]; V -> transposed [bh][d][key]
// EMODE 3: fp32 store + bias (final output)
// EMODE 4: fp32 partial store at slice blockIdx.z (split-K conv)
template <int AMODE, int EMODE>
__global__ __launch_bounds__(256, 2) void k_gemm(
    const bf16* __restrict__ A, const bf16* __restrict__ Bt,
    void* __restrict__ Cout, const float* __restrict__ bias,
    int M, int N, int K) {
  constexpr int LDT = 72;  // 64 + 8 pad
  __shared__ alignas(16) bf16 As[64 * LDT];
  __shared__ alignas(16) bf16 Bs[64 * LDT];
  int tid = threadIdx.x;
  int m0 = blockIdx.x * 64, n0 = blockIdx.y * 64;
  int kbeg = blockIdx.z * K;
  int wave = tid >> 6, lane = tid & 63;
  int quad = lane >> 4, l16 = lane & 15;

  f32x4 acc[4];
#pragma unroll
  for (int i = 0; i < 4; i++) acc[i] = (f32x4){0.f, 0.f, 0.f, 0.f};

  for (int k0 = kbeg; k0 < kbeg + K; k0 += 64) {
#pragma unroll
    for (int t = 0; t < 2; t++) {
      int c = tid + t * 256;
      int row = c >> 3, c8 = (c & 7) * 8;
      const bf16* asrc;
      if constexpr (AMODE == 0) {
        asrc = A + (size_t)(m0 + row) * K + k0 + c8;
      } else {
        int m = m0 + row;
        int b = m >> 8, tt = m & 255;
        int oh = tt >> 4, ow = tt & 15;
        int p = k0 >> 8;            // patch position (BK=64 never straddles p)
        int kh = p >> 2, kw = p & 3;
        int tok = (oh * 4 + kh) * 64 + ow * 4 + kw;
        asrc = A + ((size_t)(b * 4096 + tok) << 8) + (k0 & 255) + c8;
      }
      *(bf16x8*)&As[row * LDT + c8] = *(const bf16x8*)asrc;
      *(bf16x8*)&Bs[row * LDT + c8] =
          *(const bf16x8*)(Bt + (size_t)(n0 + row) * ((AMODE == 1) ? 4096 : K) + k0 + c8);
    }
    __syncthreads();
#pragma unroll
    for (int kk = 0; kk < 64; kk += 32) {
      bf16x8 af = *(const bf16x8*)&As[(wave * 16 + l16) * LDT + kk + quad * 8];
#pragma unroll
      for (int nt = 0; nt < 4; nt++) {
        bf16x8 bfr = *(const bf16x8*)&Bs[(nt * 16 + l16) * LDT + kk + quad * 8];
        acc[nt] = MFMA16(af, bfr, acc[nt]);
      }
    }
    __syncthreads();
  }

  int rbase = m0 + wave * 16 + quad * 4;
#pragma unroll
  for (int nt = 0; nt < 4; nt++) {
    int col = n0 + nt * 16 + l16;
#pragma unroll
    for (int r = 0; r < 4; r++) {
      float v = acc[nt][r];
      int row = rbase + r;
      if constexpr (EMODE == 2) {
        int b = row >> 8, key = row & 255;
        int isv = col >> 8, c2 = col & 255;
        int hh = c2 >> 6, d = c2 & 63;
        int bh = b * 4 + hh;
        bf16* dst = (bf16*)Cout;
        if (isv == 0)
          dst[(((size_t)bh) * 256 + key) * 64 + d] = (bf16)v;                  // K [bh][key][d]
        else
          dst[32 * 256 * 64 + (((size_t)bh) * 64 + d) * 256 + key] = (bf16)v;  // V^T [bh][d][key]
      } else if constexpr (EMODE == 3) {
        ((float*)Cout)[(size_t)row * N + col] = v + bias[col];
      } else {  // EMODE 4
        ((float*)Cout)[((size_t)blockIdx.z * M + row) * N + col] = v;
      }
    }
  }
}

// ---------------- LayerNorm (sum of 8 fp32 partials + sr_b -> bf16) ----------------
__global__ void k_ln(const float* __restrict__ part, const float* __restrict__ srb,
                     const float* __restrict__ g, const float* __restrict__ bb,
                     bf16* __restrict__ out) {
  int row = blockIdx.x * 4 + (threadIdx.x >> 6);
  int lane = threadIdx.x & 63;
  size_t off = (size_t)row * 256 + lane * 4;
  float4 v = *(const float4*)&part[off];
#pragma unroll
  for (int z = 1; z < 8; z++) {
    float4 p = *(const float4*)&part[(size_t)z * 2048 * 256 + off];
    v.x += p.x; v.y += p.y; v.z += p.z; v.w += p.w;
  }
  int c = lane * 4;
  v.x += srb[c + 0]; v.y += srb[c + 1]; v.z += srb[c + 2]; v.w += srb[c + 3];
  float s = v.x + v.y + v.z + v.w;
#pragma unroll
  for (int i = 1; i < 64; i <<= 1) s += __shfl_xor(s, i, 64);
  float mu = s * (1.f / 256.f);
  float d0 = v.x - mu, d1 = v.y - mu, d2 = v.z - mu, d3 = v.w - mu;
  float q = d0 * d0 + d1 * d1 + d2 * d2 + d3 * d3;
#pragma unroll
  for (int i = 1; i < 64; i <<= 1) q += __shfl_xor(q, i, 64);
  float rs = rsqrtf(q * (1.f / 256.f) + 1e-5f);
  bf16x4 o;
  o[0] = (bf16)(d0 * rs * g[c + 0] + bb[c + 0]);
  o[1] = (bf16)(d1 * rs * g[c + 1] + bb[c + 1]);
  o[2] = (bf16)(d2 * rs * g[c + 2] + bb[c + 2]);
  o[3] = (bf16)(d3 * rs * g[c + 3] + bb[c + 3]);
  *(bf16x4*)&out[(size_t)row * 256 + c] = o;
}

// ---------------- attention with fused Q-projection ----------------
// grid (32 bh, 64 qtiles), block 256 (4 waves)
// All MFMA operands except the two lane-transposes (Q, P) are read directly
// from global memory in fragment layout (K/V/WqT are L2-resident; x read once).
// LDS: single [64][264] buffer; Qs [64][72] aliases it (one barrier between
// last Qs read and first Ps write; all other LDS traffic is wave-private rows).
__global__ __launch_bounds__(256, 4) void k_attn(
    const bf16* __restrict__ xbf,  // [B*4096][256]
    const bf16* __restrict__ WqT,  // [256 out][256 in]
    const bf16* __restrict__ Kb,   // [32][256][64]
    const bf16* __restrict__ Vt_g, // [32][64][256]  (V^T)
    bf16* __restrict__ O) {        // [B*4096][256]
  int bh = blockIdx.x, qt = blockIdx.y;
  int b = bh >> 2, h = bh & 3;
  int tid = threadIdx.x, wave = tid >> 6, lane = tid & 63;
  int quad = lane >> 4, l16 = lane & 15;

  __shared__ alignas(16) bf16 smem[64 * 264];  // Ps[64][264]; Qs[64][72] aliases

  // ---- phase 1: Q = x_tile @ WqT[head], fragments straight from global ----
  const bf16* xrow =
      xbf + (((size_t)(b * 4096 + qt * 64 + wave * 16 + l16)) << 8) + quad * 8;
  const bf16* wq = WqT + (((size_t)(h * 64)) << 8) + quad * 8;
  f32x4 q[4];
#pragma unroll
  for (int i = 0; i < 4; i++) q[i] = (f32x4){0.f, 0.f, 0.f, 0.f};
#pragma unroll
  for (int k0 = 0; k0 < 256; k0 += 32) {
    bf16x8 ax = *(const bf16x8*)(xrow + k0);
#pragma unroll
    for (int nt = 0; nt < 4; nt++) {
      bf16x8 bw = *(const bf16x8*)(wq + ((nt * 16 + l16) << 8) + k0);
      q[nt] = MFMA16(ax, bw, q[nt]);
    }
  }

  // write Q (C-layout -> Qs row-major [q][d], stride 72) — wave-private rows
#pragma unroll
  for (int nt = 0; nt < 4; nt++)
#pragma unroll
    for (int r = 0; r < 4; r++)
      smem[(wave * 16 + quad * 4 + r) * 72 + nt * 16 + l16] = (bf16)q[nt][r];

  bf16x8 aq0 = *(const bf16x8*)&smem[(wave * 16 + l16) * 72 + 0 + quad * 8];
  bf16x8 aq1 = *(const bf16x8*)&smem[(wave * 16 + l16) * 72 + 32 + quad * 8];

  // ---- phase 2: S = Q K^T (K fragments from global, L2-hot) ----
  const bf16* Kbh = Kb + (((size_t)bh) << 14) + quad * 8;  // 256*64 per bh
  f32x4 s[16];
#pragma unroll
  for (int i = 0; i < 16; i++) s[i] = (f32x4){0.f, 0.f, 0.f, 0.f};
#pragma unroll
  for (int nt = 0; nt < 16; nt++) {
    bf16x8 b0 = *(const bf16x8*)(Kbh + ((nt * 16 + l16) << 6));
    bf16x8 b1 = *(const bf16x8*)(Kbh + ((nt * 16 + l16) << 6) + 32);
    s[nt] = MFMA16(aq0, b0, s[nt]);
    s[nt] = MFMA16(aq1, b1, s[nt]);
  }

  // softmax over 256 keys (keys live on l16 within each quad's 4 q-rows)
  const float scale = 0.125f;
#pragma unroll
  for (int r = 0; r < 4; r++) {
    float m = -1e30f;
#pragma unroll
    for (int nt = 0; nt < 16; nt++) m = fmaxf(m, s[nt][r]);
#pragma unroll
    for (int i = 1; i < 16; i <<= 1) m = fmaxf(m, __shfl_xor(m, i, 64));
    float sum = 0.f;
#pragma unroll
    for (int nt = 0; nt < 16; nt++) {
      float e = __expf((s[nt][r] - m) * scale);
      s[nt][r] = e;
      sum += e;
    }
#pragma unroll
    for (int i = 1; i < 16; i <<= 1) sum += __shfl_xor(sum, i, 64);
    float inv = 1.f / sum;
#pragma unroll
    for (int nt = 0; nt < 16; nt++) s[nt][r] *= inv;
  }

  // all waves finished reading Qs (consumed before MFMAs above); Ps overwrites it
  __syncthreads();
#pragma unroll
  for (int nt = 0; nt < 16; nt++)
#pragma unroll
    for (int r = 0; r < 4; r++)
      smem[(wave * 16 + quad * 4 + r) * 264 + nt * 16 + l16] = (bf16)s[nt][r];
  // Ps reads below are wave-private rows -> no barrier needed

  // ---- phase 3: O = P V  (V^T fragments from global, L2-hot) ----
  const bf16* Vbh = Vt_g + (((size_t)bh) << 14) + quad * 8;
  f32x4 o[4];
#pragma unroll
  for (int i = 0; i < 4; i++) o[i] = (f32x4){0.f, 0.f, 0.f, 0.f};
#pragma unroll
  for (int k0 = 0; k0 < 256; k0 += 32) {
    bf16x8 ap = *(const bf16x8*)&smem[(wave * 16 + l16) * 264 + k0 + quad * 8];
#pragma unroll
    for (int nt = 0; nt < 4; nt++) {
      bf16x8 bv = *(const bf16x8*)(Vbh + ((nt * 16 + l16) << 8) + k0);
      o[nt] = MFMA16(ap, bv, o[nt]);
    }
  }

  size_t orow = (size_t)b * 4096 + qt * 64 + wave * 16 + quad * 4;
#pragma unroll
  for (int nt = 0; nt < 4; nt++) {
    int col = h * 64 + nt * 16 + l16;
#pragma unroll
    for (int r = 0; r < 4; r++) O[(orow + r) * 256 + col] = (bf16)o[nt][r];
  }
}

// ---------------- launch ----------------
extern "C" void kernel_launch(void* const* d_in, const int* in_sizes, int n_in,
                              void* d_out, int out_size, void* d_ws, size_t ws_size,
                              hipStream_t stream) {
  (void)in_sizes; (void)n_in; (void)out_size; (void)ws_size;
  const float* x   = (const float*)d_in[0];
  const float* Wq  = (const float*)d_in[3];
  const float* Wkv = (const float*)d_in[4];
  const float* srw = (const float*)d_in[5];
  const float* srb = (const float*)d_in[6];
  const float* lng = (const float*)d_in[7];
  const float* lnb = (const float*)d_in[8];
  const float* Wo  = (const float*)d_in[9];
  const float* bo  = (const float*)d_in[10];
  float* out = (float*)d_out;

  char* ws = (char*)d_ws;
  bf16*  x_bf  = (bf16*)(ws + 0);          // 16,777,216 B
  bf16*  AObuf = (bf16*)(ws + 16777216);   // 16,777,216
  float* convp = (float*)(ws + 33554432);  // 16,777,216 (8 partials)
  bf16*  WqT   = (bf16*)(ws + 50331648);   //    131,072
  bf16*  WkvT  = (bf16*)(ws + 50462720);   //    262,144
  bf16*  WoT   = (bf16*)(ws + 50724864);   //    131,072
  bf16*  srwT  = (bf16*)(ws + 50855936);   //  2,097,152
  bf16*  xln   = (bf16*)(ws + 52953088);   //  1,048,576
  bf16*  kvbuf = (bf16*)(ws + 54001664);   //  2,097,152 (K then V^T)

  k_prep<<<10240, 256, 0, stream>>>(x, Wq, Wkv, Wo, srw, x_bf, WqT, WkvT, WoT, srwT);
  // conv (im2col GEMM), split-K 8x512 -> fp32 partials [8][2048][256]
  k_gemm<1, 4><<<dim3(32, 4, 8), 256, 0, stream>>>(x_bf, srwT, convp, nullptr, 2048, 256, 512);
  // LayerNorm (+partial reduce +sr_b) -> bf16 [2048][256]
  k_ln<<<512, 256, 0, stream>>>(convp, srb, lng, lnb, xln);
  // KV = xln @ Wkv -> K [32][256][64], V^T [32][64][256] bf16
  k_gemm<0, 2><<<dim3(32, 8), 256, 0, stream>>>(xln, WkvT, kvbuf, nullptr, 2048, 512, 256);
  // attention (Q-proj fused)
  k_attn<<<dim3(32, 64), 256, 0, stream>>>(x_bf, WqT, kvbuf, kvbuf + (size_t)32 * 256 * 64, AObuf);
  // out = AO @ Wo + bo -> fp32 d_out
  k_gemm<0, 3><<<dim3(512, 4), 256, 0, stream>>>(AObuf, WoT, out, bo, 32768, 256, 256);
}

// Round 2
// 187.838 us; speedup vs baseline: 1.2988x; 1.2988x over previous
//
#include <hip/hip_runtime.h>

typedef __bf16 bf16;
typedef bf16 bf16x8 __attribute__((ext_vector_type(8)));
typedef bf16 bf16x4 __attribute__((ext_vector_type(4)));
typedef float f32x4 __attribute__((ext_vector_type(4)));

#define MFMA16(a, b, c) __builtin_amdgcn_mfma_f32_16x16x32_bf16(a, b, c, 0, 0, 0)

// async global->LDS, 16B per lane; lds dest must be wave-uniform base (+lane*16 by HW)
__device__ __forceinline__ void gload_lds16(const bf16* g, bf16* l) {
  __builtin_amdgcn_global_load_lds(
      (const __attribute__((address_space(1))) void*)g,
      (__attribute__((address_space(3))) void*)l, 16, 0, 0);
}

// ---------------- merged prep kernel ----------------
__global__ void k_prep(const float* __restrict__ x, const float* __restrict__ Wq,
                       const float* __restrict__ Wkv, const float* __restrict__ Wo,
                       const float* __restrict__ srw,
                       bf16* __restrict__ x_bf, bf16* __restrict__ WqT,
                       bf16* __restrict__ WkvT, bf16* __restrict__ WoT,
                       bf16* __restrict__ srwT) {
  int bid = blockIdx.x, tid = threadIdx.x;
  if (bid < 8192) {
    int i = (bid * 256 + tid) * 4;
    float4 v = *(const float4*)(x + i);
    bf16x4 o;
    o[0] = (bf16)v.x; o[1] = (bf16)v.y; o[2] = (bf16)v.z; o[3] = (bf16)v.w;
    *(bf16x4*)(x_bf + i) = o;
  } else if (bid < 9216) {
    int id = (bid - 8192) * 256 + tid;  // 0..262143
    if (id < 65536) {                   // WqT
      int c = id >> 8, r = id & 255;
      WqT[id] = (bf16)Wq[r * 256 + c];
    } else if (id < 196608) {           // WkvT
      int l = id - 65536;
      int c = l >> 8, r = l & 255;      // c in 0..511
      WkvT[l] = (bf16)Wkv[r * 512 + c];
    } else {                            // WoT
      int l = id - 196608;
      int c = l >> 8, r = l & 255;
      WoT[l] = (bf16)Wo[r * 256 + c];
    }
  } else {
    int id4 = ((bid - 9216) * 256 + tid) * 4;  // input-linear o*4096+i*16+p
    int o = id4 >> 12, rem = id4 & 4095;
    int i = rem >> 4, p = rem & 15;            // p in {0,4,8,12}
    float4 v = *(const float4*)(srw + id4);
    srwT[(o << 12) + ((p + 0) << 8) + i] = (bf16)v.x;
    srwT[(o << 12) + ((p + 1) << 8) + i] = (bf16)v.y;
    srwT[(o << 12) + ((p + 2) << 8) + i] = (bf16)v.z;
    srwT[(o << 12) + ((p + 3) << 8) + i] = (bf16)v.w;
  }
}

// ---------------- generic MFMA GEMM ----------------
// C[M][N] = A[M][K] @ Bt[N][K]^T   (bf16 inputs, fp32 accum)
// AMODE 0: A row-major [M][K]
// AMODE 1: conv im2col gather from x_bf [B*4096][256]; K index = p*256 + i
// EMODE 2: KV scatter (XOR-swizzled cols for attn's global_load_lds staging):
//          K  -> [bh][key][d ^ ((key&7)<<3)]
//          V^T-> [bh][d][key ^ ((d&7)<<3)]
// EMODE 3: fp32 store + bias (final output)
// EMODE 4: fp32 partial store at slice blockIdx.z (split-K conv)
// EMODE 5: Q scatter -> [bh][token][d] (unswizzled; read to regs in attn)
template <int AMODE, int EMODE>
__global__ __launch_bounds__(256, 2) void k_gemm(
    const bf16* __restrict__ A, const bf16* __restrict__ Bt,
    void* __restrict__ Cout, const float* __restrict__ bias,
    int M, int N, int K) {
  constexpr int LDT = 72;  // 64 + 8 pad
  __shared__ alignas(16) bf16 As[64 * LDT];
  __shared__ alignas(16) bf16 Bs[64 * LDT];
  int tid = threadIdx.x;
  int m0 = blockIdx.x * 64, n0 = blockIdx.y * 64;
  int kbeg = blockIdx.z * K;
  int wave = tid >> 6, lane = tid & 63;
  int quad = lane >> 4, l16 = lane & 15;

  f32x4 acc[4];
#pragma unroll
  for (int i = 0; i < 4; i++) acc[i] = (f32x4){0.f, 0.f, 0.f, 0.f};

  for (int k0 = kbeg; k0 < kbeg + K; k0 += 64) {
#pragma unroll
    for (int t = 0; t < 2; t++) {
      int c = tid + t * 256;
      int row = c >> 3, c8 = (c & 7) * 8;
      const bf16* asrc;
      if constexpr (AMODE == 0) {
        asrc = A + (size_t)(m0 + row) * K + k0 + c8;
      } else {
        int m = m0 + row;
        int b = m >> 8, tt = m & 255;
        int oh = tt >> 4, ow = tt & 15;
        int p = k0 >> 8;            // patch position (BK=64 never straddles p)
        int kh = p >> 2, kw = p & 3;
        int tok = (oh * 4 + kh) * 64 + ow * 4 + kw;
        asrc = A + ((size_t)(b * 4096 + tok) << 8) + (k0 & 255) + c8;
      }
      *(bf16x8*)&As[row * LDT + c8] = *(const bf16x8*)asrc;
      *(bf16x8*)&Bs[row * LDT + c8] =
          *(const bf16x8*)(Bt + (size_t)(n0 + row) * ((AMODE == 1) ? 4096 : K) + k0 + c8);
    }
    __syncthreads();
#pragma unroll
    for (int kk = 0; kk < 64; kk += 32) {
      bf16x8 af = *(const bf16x8*)&As[(wave * 16 + l16) * LDT + kk + quad * 8];
#pragma unroll
      for (int nt = 0; nt < 4; nt++) {
        bf16x8 bfr = *(const bf16x8*)&Bs[(nt * 16 + l16) * LDT + kk + quad * 8];
        acc[nt] = MFMA16(af, bfr, acc[nt]);
      }
    }
    __syncthreads();
  }

  int rbase = m0 + wave * 16 + quad * 4;
#pragma unroll
  for (int nt = 0; nt < 4; nt++) {
    int col = n0 + nt * 16 + l16;
#pragma unroll
    for (int r = 0; r < 4; r++) {
      float v = acc[nt][r];
      int row = rbase + r;
      if constexpr (EMODE == 2) {
        int b = row >> 8, key = row & 255;
        int isv = col >> 8, c2 = col & 255;
        int hh = c2 >> 6, d = c2 & 63;
        int bh = b * 4 + hh;
        bf16* dst = (bf16*)Cout;
        if (isv == 0)
          dst[(((size_t)bh) * 256 + key) * 64 + (d ^ ((key & 7) << 3))] = (bf16)v;
        else
          dst[32 * 256 * 64 + (((size_t)bh) * 64 + d) * 256 + (key ^ ((d & 7) << 3))] = (bf16)v;
      } else if constexpr (EMODE == 3) {
        ((float*)Cout)[(size_t)row * N + col] = v + bias[col];
      } else if constexpr (EMODE == 5) {
        int b2 = row >> 12, tok = row & 4095;
        int hh = col >> 6, d = col & 63;
        ((bf16*)Cout)[(((size_t)(b2 * 4 + hh)) * 4096 + tok) * 64 + d] = (bf16)v;
      } else {  // EMODE 4
        ((float*)Cout)[((size_t)blockIdx.z * M + row) * N + col] = v;
      }
    }
  }
}

// ---------------- LayerNorm (sum of 8 fp32 partials + sr_b -> bf16) ----------------
__global__ void k_ln(const float* __restrict__ part, const float* __restrict__ srb,
                     const float* __restrict__ g, const float* __restrict__ bb,
                     bf16* __restrict__ out) {
  int row = blockIdx.x * 4 + (threadIdx.x >> 6);
  int lane = threadIdx.x & 63;
  size_t off = (size_t)row * 256 + lane * 4;
  float4 v = *(const float4*)&part[off];
#pragma unroll
  for (int z = 1; z < 8; z++) {
    float4 p = *(const float4*)&part[(size_t)z * 2048 * 256 + off];
    v.x += p.x; v.y += p.y; v.z += p.z; v.w += p.w;
  }
  int c = lane * 4;
  v.x += srb[c + 0]; v.y += srb[c + 1]; v.z += srb[c + 2]; v.w += srb[c + 3];
  float s = v.x + v.y + v.z + v.w;
#pragma unroll
  for (int i = 1; i < 64; i <<= 1) s += __shfl_xor(s, i, 64);
  float mu = s * (1.f / 256.f);
  float d0 = v.x - mu, d1 = v.y - mu, d2 = v.z - mu, d3 = v.w - mu;
  float q = d0 * d0 + d1 * d1 + d2 * d2 + d3 * d3;
#pragma unroll
  for (int i = 1; i < 64; i <<= 1) q += __shfl_xor(q, i, 64);
  float rs = rsqrtf(q * (1.f / 256.f) + 1e-5f);
  bf16x4 o;
  o[0] = (bf16)(d0 * rs * g[c + 0] + bb[c + 0]);
  o[1] = (bf16)(d1 * rs * g[c + 1] + bb[c + 1]);
  o[2] = (bf16)(d2 * rs * g[c + 2] + bb[c + 2]);
  o[3] = (bf16)(d3 * rs * g[c + 3] + bb[c + 3]);
  *(bf16x4*)&out[(size_t)row * 256 + c] = o;
}

// ---------------- attention (Q precomputed) ----------------
// grid (32 bh, 64 qtiles), block 256 (4 waves), LDS 48 KiB -> 3 blocks/CU
// Q read straight to regs (2x16B/lane). K (32K) + V^T half (16K) staged via
// global_load_lds from pre-swizzled global; ds_reads apply the XOR (~2-way).
// P aliases K's LDS after QK^T (single barrier; P rows are wave-private).
__global__ __launch_bounds__(256, 3) void k_attn(
    const bf16* __restrict__ Qg,   // [32 bh][4096][64]
    const bf16* __restrict__ Kg,   // [32][256][64]  cols ^ ((key&7)<<3)
    const bf16* __restrict__ Vg,   // [32][64][256]  cols ^ ((d&7)<<3)
    bf16* __restrict__ O) {        // [B*4096][256]
  int bh = blockIdx.x, qt = blockIdx.y;
  int b = bh >> 2, h = bh & 3;
  int tid = threadIdx.x, wave = tid >> 6, lane = tid & 63;
  int quad = lane >> 4, l16 = lane & 15;

  __shared__ alignas(16) bf16 smem[24576];  // 49152 B
  bf16* Ks = smem;          // [256][64] swizzled; becomes Ps[64][256] swizzled
  bf16* Vs = smem + 16384;  // [64][128] swizzled key-half

  const bf16* Kbh = Kg + ((size_t)bh << 14);
  const bf16* Vbh = Vg + ((size_t)bh << 14);

  // ---- stage K (32 chunks x 1KiB) + V half0 (16 chunks) ----
#pragma unroll
  for (int t = 0; t < 8; t++) {
    int chunk = t * 4 + wave;
    gload_lds16(Kbh + chunk * 512 + lane * 8, Ks + chunk * 512);
  }
#pragma unroll
  for (int t = 0; t < 4; t++) {
    int chunk = t * 4 + wave;
    gload_lds16(Vbh + (chunk * 4 + (lane >> 4)) * 256 + (lane & 15) * 8,
                Vs + chunk * 512);
  }

  // ---- Q fragments straight from global (row-contiguous) ----
  const bf16* qrow =
      Qg + (((size_t)bh * 4096) + qt * 64 + wave * 16 + l16) * 64 + quad * 8;
  bf16x8 aq0 = *(const bf16x8*)(qrow);
  bf16x8 aq1 = *(const bf16x8*)(qrow + 32);

  __syncthreads();  // drains vmcnt: K + Vhalf0 resident

  // ---- S = Q K^T ----
  f32x4 s[16];
#pragma unroll
  for (int i = 0; i < 16; i++) s[i] = (f32x4){0.f, 0.f, 0.f, 0.f};
#pragma unroll
  for (int nt = 0; nt < 16; nt++) {
    int krow = nt * 16 + l16;
    const bf16* kb = Ks + krow * 64;
    int sw = (krow & 7) << 3;
    bf16x8 b0 = *(const bf16x8*)(kb + ((quad * 8) ^ sw));
    bf16x8 b1 = *(const bf16x8*)(kb + ((32 + quad * 8) ^ sw));
    s[nt] = MFMA16(aq0, b0, s[nt]);
    s[nt] = MFMA16(aq1, b1, s[nt]);
  }

  // softmax over 256 keys
  const float scale = 0.125f;
#pragma unroll
  for (int r = 0; r < 4; r++) {
    float m = -1e30f;
#pragma unroll
    for (int nt = 0; nt < 16; nt++) m = fmaxf(m, s[nt][r]);
#pragma unroll
    for (int i = 1; i < 16; i <<= 1) m = fmaxf(m, __shfl_xor(m, i, 64));
    float sum = 0.f;
#pragma unroll
    for (int nt = 0; nt < 16; nt++) {
      float e = __expf((s[nt][r] - m) * scale);
      s[nt][r] = e;
      sum += e;
    }
#pragma unroll
    for (int i = 1; i < 16; i <<= 1) sum += __shfl_xor(sum, i, 64);
    float inv = 1.f / sum;
#pragma unroll
    for (int nt = 0; nt < 16; nt++) s[nt][r] *= inv;
  }

  __syncthreads();  // all QK^T reads of Ks done; Ps overwrites it

  // ---- write P [64][256] swizzled (wave-private rows; no barrier after) ----
#pragma unroll
  for (int nt = 0; nt < 16; nt++)
#pragma unroll
    for (int r = 0; r < 4; r++) {
      int prow = wave * 16 + quad * 4 + r;
      Ks[prow * 256 + ((nt * 16 + l16) ^ ((prow & 7) << 3))] = (bf16)s[nt][r];
    }

  // ---- O = P V, keys 0..127 from Vs half0 ----
  int arow = wave * 16 + l16;
  int asw = (arow & 7) << 3;
  const bf16* pb = Ks + arow * 256;
  f32x4 o[4];
#pragma unroll
  for (int i = 0; i < 4; i++) o[i] = (f32x4){0.f, 0.f, 0.f, 0.f};
#pragma unroll
  for (int k0 = 0; k0 < 128; k0 += 32) {
    bf16x8 ap = *(const bf16x8*)(pb + ((k0 + quad * 8) ^ asw));
#pragma unroll
    for (int nt = 0; nt < 4; nt++) {
      int vrow = nt * 16 + l16;
      bf16x8 bv = *(const bf16x8*)(Vs + vrow * 128 + ((k0 + quad * 8) ^ ((vrow & 7) << 3)));
      o[nt] = MFMA16(ap, bv, o[nt]);
    }
  }

  __syncthreads();  // all reads of Vs half0 done
#pragma unroll
  for (int t = 0; t < 4; t++) {
    int chunk = t * 4 + wave;
    gload_lds16(Vbh + (chunk * 4 + (lane >> 4)) * 256 + 128 + (lane & 15) * 8,
                Vs + chunk * 512);
  }
  __syncthreads();  // drain: Vhalf1 resident

  // ---- keys 128..255 from Vs half1 ----
#pragma unroll
  for (int k0 = 128; k0 < 256; k0 += 32) {
    bf16x8 ap = *(const bf16x8*)(pb + ((k0 + quad * 8) ^ asw));
    int kl = k0 - 128;
#pragma unroll
    for (int nt = 0; nt < 4; nt++) {
      int vrow = nt * 16 + l16;
      bf16x8 bv = *(const bf16x8*)(Vs + vrow * 128 + ((kl + quad * 8) ^ ((vrow & 7) << 3)));
      o[nt] = MFMA16(ap, bv, o[nt]);
    }
  }

  size_t orow = (size_t)b * 4096 + qt * 64 + wave * 16 + quad * 4;
#pragma unroll
  for (int nt = 0; nt < 4; nt++) {
    int col = h * 64 + nt * 16 + l16;
#pragma unroll
    for (int r = 0; r < 4; r++) O[(orow + r) * 256 + col] = (bf16)o[nt][r];
  }
}

// ---------------- launch ----------------
extern "C" void kernel_launch(void* const* d_in, const int* in_sizes, int n_in,
                              void* d_out, int out_size, void* d_ws, size_t ws_size,
                              hipStream_t stream) {
  (void)in_sizes; (void)n_in; (void)out_size; (void)ws_size;
  const float* x   = (const float*)d_in[0];
  const float* Wq  = (const float*)d_in[3];
  const float* Wkv = (const float*)d_in[4];
  const float* srw = (const float*)d_in[5];
  const float* srb = (const float*)d_in[6];
  const float* lng = (const float*)d_in[7];
  const float* lnb = (const float*)d_in[8];
  const float* Wo  = (const float*)d_in[9];
  const float* bo  = (const float*)d_in[10];
  float* out = (float*)d_out;

  char* ws = (char*)d_ws;
  bf16*  x_bf  = (bf16*)(ws + 0);          // 16,777,216 B
  bf16*  AObuf = (bf16*)(ws + 16777216);   // 16,777,216
  float* convp = (float*)(ws + 33554432);  // 16,777,216 (8 partials; dead after k_ln)
  bf16*  qbuf  = (bf16*)(ws + 33554432);   // aliases convp: Q [32][4096][64]
  bf16*  WqT   = (bf16*)(ws + 50331648);   //    131,072
  bf16*  WkvT  = (bf16*)(ws + 50462720);   //    262,144
  bf16*  WoT   = (bf16*)(ws + 50724864);   //    131,072
  bf16*  srwT  = (bf16*)(ws + 50855936);   //  2,097,152
  bf16*  xln   = (bf16*)(ws + 52953088);   //  1,048,576
  bf16*  kvbuf = (bf16*)(ws + 54001664);   //  2,097,152 (K then V^T, swizzled)

  k_prep<<<10240, 256, 0, stream>>>(x, Wq, Wkv, Wo, srw, x_bf, WqT, WkvT, WoT, srwT);
  // conv (im2col GEMM), split-K 8x512 -> fp32 partials [8][2048][256]
  k_gemm<1, 4><<<dim3(32, 4, 8), 256, 0, stream>>>(x_bf, srwT, convp, nullptr, 2048, 256, 512);
  // LayerNorm (+partial reduce +sr_b) -> bf16 [2048][256]
  k_ln<<<512, 256, 0, stream>>>(convp, srb, lng, lnb, xln);
  // KV = xln @ Wkv -> K, V^T (swizzled) bf16
  k_gemm<0, 2><<<dim3(32, 8), 256, 0, stream>>>(xln, WkvT, kvbuf, nullptr, 2048, 512, 256);
  // Q = x @ Wq -> [bh][tok][64] (into convp space, now free)
  k_gemm<0, 5><<<dim3(512, 4), 256, 0, stream>>>(x_bf, WqT, qbuf, nullptr, 32768, 256, 256);
  // attention
  k_attn<<<dim3(32, 64), 256, 0, stream>>>(qbuf, kvbuf, kvbuf + (size_t)32 * 256 * 64, AObuf);
  // out = AO @ Wo + bo -> fp32 d_out
  k_gemm<0, 3><<<dim3(512, 4), 256, 0, stream>>>(AObuf, WoT, out, bo, 32768, 256, 256);
}

// Round 3
// 181.690 us; speedup vs baseline: 1.3428x; 1.0338x over previous
//
#include <hip/hip_runtime.h>

typedef __bf16 bf16;
typedef bf16 bf16x8 __attribute__((ext_vector_type(8)));
typedef bf16 bf16x4 __attribute__((ext_vector_type(4)));
typedef float f32x4 __attribute__((ext_vector_type(4)));

#define MFMA16(a, b, c) __builtin_amdgcn_mfma_f32_16x16x32_bf16(a, b, c, 0, 0, 0)

// async global->LDS, 16B per lane; lds dest is wave-uniform base (+lane*16 by HW)
__device__ __forceinline__ void gload_lds16(const bf16* g, bf16* l) {
  __builtin_amdgcn_global_load_lds(
      (const __attribute__((address_space(1))) void*)g,
      (__attribute__((address_space(3))) void*)l, 16, 0, 0);
}

// ---------------- merged prep kernel ----------------
__global__ void k_prep(const float* __restrict__ x, const float* __restrict__ Wq,
                       const float* __restrict__ Wkv, const float* __restrict__ Wo,
                       const float* __restrict__ srw,
                       bf16* __restrict__ x_bf, bf16* __restrict__ WqT,
                       bf16* __restrict__ WkvT, bf16* __restrict__ WoT,
                       bf16* __restrict__ srwT) {
  int bid = blockIdx.x, tid = threadIdx.x;
  if (bid < 8192) {
    int i = (bid * 256 + tid) * 4;
    float4 v = *(const float4*)(x + i);
    bf16x4 o;
    o[0] = (bf16)v.x; o[1] = (bf16)v.y; o[2] = (bf16)v.z; o[3] = (bf16)v.w;
    *(bf16x4*)(x_bf + i) = o;
  } else if (bid < 9216) {
    int id = (bid - 8192) * 256 + tid;  // 0..262143
    if (id < 65536) {                   // WqT
      int c = id >> 8, r = id & 255;
      WqT[id] = (bf16)Wq[r * 256 + c];
    } else if (id < 196608) {           // WkvT
      int l = id - 65536;
      int c = l >> 8, r = l & 255;      // c in 0..511
      WkvT[l] = (bf16)Wkv[r * 512 + c];
    } else {                            // WoT
      int l = id - 196608;
      int c = l >> 8, r = l & 255;
      WoT[l] = (bf16)Wo[r * 256 + c];
    }
  } else {
    int id4 = ((bid - 9216) * 256 + tid) * 4;  // input-linear o*4096+i*16+p
    int o = id4 >> 12, rem = id4 & 4095;
    int i = rem >> 4, p = rem & 15;            // p in {0,4,8,12}
    float4 v = *(const float4*)(srw + id4);
    srwT[(o << 12) + ((p + 0) << 8) + i] = (bf16)v.x;
    srwT[(o << 12) + ((p + 1) << 8) + i] = (bf16)v.y;
    srwT[(o << 12) + ((p + 2) << 8) + i] = (bf16)v.z;
    srwT[(o << 12) + ((p + 3) << 8) + i] = (bf16)v.w;
  }
}

// ---------------- 64x64-tile MFMA GEMM (kept for the small KV GEMM) ----------------
// EMODE 2: KV scatter (XOR-swizzled cols for attn's global_load_lds staging):
//          K  -> [bh][key][d ^ ((key&7)<<3)]
//          V^T-> [bh][d][key ^ ((d&7)<<3)]
template <int AMODE, int EMODE>
__global__ __launch_bounds__(256, 2) void k_gemm(
    const bf16* __restrict__ A, const bf16* __restrict__ Bt,
    void* __restrict__ Cout, const float* __restrict__ bias,
    int M, int N, int K) {
  constexpr int LDT = 72;  // 64 + 8 pad
  __shared__ alignas(16) bf16 As[64 * LDT];
  __shared__ alignas(16) bf16 Bs[64 * LDT];
  int tid = threadIdx.x;
  int m0 = blockIdx.x * 64, n0 = blockIdx.y * 64;
  int kbeg = blockIdx.z * K;
  int wave = tid >> 6, lane = tid & 63;
  int quad = lane >> 4, l16 = lane & 15;

  f32x4 acc[4];
#pragma unroll
  for (int i = 0; i < 4; i++) acc[i] = (f32x4){0.f, 0.f, 0.f, 0.f};

  for (int k0 = kbeg; k0 < kbeg + K; k0 += 64) {
#pragma unroll
    for (int t = 0; t < 2; t++) {
      int c = tid + t * 256;
      int row = c >> 3, c8 = (c & 7) * 8;
      *(bf16x8*)&As[row * LDT + c8] =
          *(const bf16x8*)(A + (size_t)(m0 + row) * K + k0 + c8);
      *(bf16x8*)&Bs[row * LDT + c8] =
          *(const bf16x8*)(Bt + (size_t)(n0 + row) * K + k0 + c8);
    }
    __syncthreads();
#pragma unroll
    for (int kk = 0; kk < 64; kk += 32) {
      bf16x8 af = *(const bf16x8*)&As[(wave * 16 + l16) * LDT + kk + quad * 8];
#pragma unroll
      for (int nt = 0; nt < 4; nt++) {
        bf16x8 bfr = *(const bf16x8*)&Bs[(nt * 16 + l16) * LDT + kk + quad * 8];
        acc[nt] = MFMA16(af, bfr, acc[nt]);
      }
    }
    __syncthreads();
  }

  int rbase = m0 + wave * 16 + quad * 4;
#pragma unroll
  for (int nt = 0; nt < 4; nt++) {
    int col = n0 + nt * 16 + l16;
#pragma unroll
    for (int r = 0; r < 4; r++) {
      float v = acc[nt][r];
      int row = rbase + r;
      if constexpr (EMODE == 2) {
        int b = row >> 8, key = row & 255;
        int isv = col >> 8, c2 = col & 255;
        int hh = c2 >> 6, d = c2 & 63;
        int bh = b * 4 + hh;
        bf16* dst = (bf16*)Cout;
        if (isv == 0)
          dst[(((size_t)bh) * 256 + key) * 64 + (d ^ ((key & 7) << 3))] = (bf16)v;
        else
          dst[32 * 256 * 64 + (((size_t)bh) * 64 + d) * 256 + (key ^ ((d & 7) << 3))] = (bf16)v;
      } else {
        ((float*)Cout)[(size_t)row * N + col] = v + bias[col];
      }
    }
  }
}

// ---------------- 128x128-tile MFMA GEMM (m97 structure) ----------------
// 4 waves; wave (wr,wc) owns a 64x64 quadrant; acc 4x4 f32x4.
// LDS: As[128][64], Bs[128][64] linear, staged via global_load_lds width=16.
// AMODE 0: A row-major [M][K]; AMODE 1: conv im2col gather from x_bf.
// EMODE 3: fp32 store + bias; EMODE 4: fp32 partial at slice z; EMODE 5: Q scatter.
template <int AMODE, int EMODE>
__global__ __launch_bounds__(256, 2) void k_gemm128(
    const bf16* __restrict__ A, const bf16* __restrict__ Bt,
    void* __restrict__ Cout, const float* __restrict__ bias,
    int M, int N, int K) {
  __shared__ alignas(16) bf16 As[128 * 64];
  __shared__ alignas(16) bf16 Bs[128 * 64];
  int tid = threadIdx.x;
  int m0 = blockIdx.x * 128, n0 = blockIdx.y * 128;
  int kbeg = blockIdx.z * K;
  int wave = tid >> 6, lane = tid & 63;
  int quad = lane >> 4, l16 = lane & 15;
  int wr = wave >> 1, wc = wave & 1;

  f32x4 acc[4][4];
#pragma unroll
  for (int i = 0; i < 4; i++)
#pragma unroll
    for (int j = 0; j < 4; j++) acc[i][j] = (f32x4){0.f, 0.f, 0.f, 0.f};

  for (int k0 = kbeg; k0 < kbeg + K; k0 += 64) {
#pragma unroll
    for (int t = 0; t < 4; t++) {
      int chunk = wave * 4 + t;            // 0..15, wave-uniform
      int row = chunk * 8 + (lane >> 3);   // 8 rows per chunk
      int c8 = (lane & 7) * 8;             // bf16 offset within row (16B/lane)
      const bf16* asrc;
      if constexpr (AMODE == 0) {
        asrc = A + (size_t)(m0 + row) * K + k0 + c8;
      } else {
        int m = m0 + row;
        int b = m >> 8, tt = m & 255;
        int oh = tt >> 4, ow = tt & 15;
        int p = k0 >> 8;            // patch position (BK=64 never straddles p)
        int kh = p >> 2, kw = p & 3;
        int tok = (oh * 4 + kh) * 64 + ow * 4 + kw;
        asrc = A + ((size_t)(b * 4096 + tok) << 8) + (k0 & 255) + c8;
      }
      gload_lds16(asrc, As + chunk * 512);
      gload_lds16(Bt + (size_t)(n0 + row) * ((AMODE == 1) ? 4096 : K) + k0 + c8,
                  Bs + chunk * 512);
    }
    __syncthreads();
#pragma unroll
    for (int kk = 0; kk < 64; kk += 32) {
      bf16x8 af[4], bfr[4];
#pragma unroll
      for (int mt = 0; mt < 4; mt++)
        af[mt] = *(const bf16x8*)&As[(wr * 64 + mt * 16 + l16) * 64 + kk + quad * 8];
#pragma unroll
      for (int nt = 0; nt < 4; nt++)
        bfr[nt] = *(const bf16x8*)&Bs[(wc * 64 + nt * 16 + l16) * 64 + kk + quad * 8];
#pragma unroll
      for (int mt = 0; mt < 4; mt++)
#pragma unroll
        for (int nt = 0; nt < 4; nt++)
          acc[mt][nt] = MFMA16(af[mt], bfr[nt], acc[mt][nt]);
    }
    __syncthreads();
  }

#pragma unroll
  for (int mt = 0; mt < 4; mt++) {
    int rbase = m0 + wr * 64 + mt * 16 + quad * 4;
#pragma unroll
    for (int nt = 0; nt < 4; nt++) {
      int col = n0 + wc * 64 + nt * 16 + l16;
#pragma unroll
      for (int r = 0; r < 4; r++) {
        float v = acc[mt][nt][r];
        int row = rbase + r;
        if constexpr (EMODE == 3) {
          ((float*)Cout)[(size_t)row * N + col] = v + bias[col];
        } else if constexpr (EMODE == 5) {
          int b2 = row >> 12, tok = row & 4095;
          int hh = col >> 6, d = col & 63;
          ((bf16*)Cout)[(((size_t)(b2 * 4 + hh)) * 4096 + tok) * 64 + d] = (bf16)v;
        } else {  // EMODE 4
          ((float*)Cout)[((size_t)blockIdx.z * M + row) * N + col] = v;
        }
      }
    }
  }
}

// ---------------- LayerNorm (sum of 8 fp32 partials + sr_b -> bf16) ----------------
__global__ void k_ln(const float* __restrict__ part, const float* __restrict__ srb,
                     const float* __restrict__ g, const float* __restrict__ bb,
                     bf16* __restrict__ out) {
  int row = blockIdx.x * 4 + (threadIdx.x >> 6);
  int lane = threadIdx.x & 63;
  size_t off = (size_t)row * 256 + lane * 4;
  float4 v = *(const float4*)&part[off];
#pragma unroll
  for (int z = 1; z < 8; z++) {
    float4 p = *(const float4*)&part[(size_t)z * 2048 * 256 + off];
    v.x += p.x; v.y += p.y; v.z += p.z; v.w += p.w;
  }
  int c = lane * 4;
  v.x += srb[c + 0]; v.y += srb[c + 1]; v.z += srb[c + 2]; v.w += srb[c + 3];
  float s = v.x + v.y + v.z + v.w;
#pragma unroll
  for (int i = 1; i < 64; i <<= 1) s += __shfl_xor(s, i, 64);
  float mu = s * (1.f / 256.f);
  float d0 = v.x - mu, d1 = v.y - mu, d2 = v.z - mu, d3 = v.w - mu;
  float q = d0 * d0 + d1 * d1 + d2 * d2 + d3 * d3;
#pragma unroll
  for (int i = 1; i < 64; i <<= 1) q += __shfl_xor(q, i, 64);
  float rs = rsqrtf(q * (1.f / 256.f) + 1e-5f);
  bf16x4 o;
  o[0] = (bf16)(d0 * rs * g[c + 0] + bb[c + 0]);
  o[1] = (bf16)(d1 * rs * g[c + 1] + bb[c + 1]);
  o[2] = (bf16)(d2 * rs * g[c + 2] + bb[c + 2]);
  o[3] = (bf16)(d3 * rs * g[c + 3] + bb[c + 3]);
  *(bf16x4*)&out[(size_t)row * 256 + c] = o;
}

// ---------------- attention (Q precomputed) ----------------
// grid (32 bh, 64 qtiles), block 256 (4 waves), LDS 48 KiB -> 3 blocks/CU
__global__ __launch_bounds__(256, 3) void k_attn(
    const bf16* __restrict__ Qg,   // [32 bh][4096][64]
    const bf16* __restrict__ Kg,   // [32][256][64]  cols ^ ((key&7)<<3)
    const bf16* __restrict__ Vg,   // [32][64][256]  cols ^ ((d&7)<<3)
    bf16* __restrict__ O) {        // [B*4096][256]
  int bh = blockIdx.x, qt = blockIdx.y;
  int b = bh >> 2, h = bh & 3;
  int tid = threadIdx.x, wave = tid >> 6, lane = tid & 63;
  int quad = lane >> 4, l16 = lane & 15;

  __shared__ alignas(16) bf16 smem[24576];  // 49152 B
  bf16* Ks = smem;          // [256][64] swizzled; becomes Ps[64][256] swizzled
  bf16* Vs = smem + 16384;  // [64][128] swizzled key-half

  const bf16* Kbh = Kg + ((size_t)bh << 14);
  const bf16* Vbh = Vg + ((size_t)bh << 14);

#pragma unroll
  for (int t = 0; t < 8; t++) {
    int chunk = t * 4 + wave;
    gload_lds16(Kbh + chunk * 512 + lane * 8, Ks + chunk * 512);
  }
#pragma unroll
  for (int t = 0; t < 4; t++) {
    int chunk = t * 4 + wave;
    gload_lds16(Vbh + (chunk * 4 + (lane >> 4)) * 256 + (lane & 15) * 8,
                Vs + chunk * 512);
  }

  const bf16* qrow =
      Qg + (((size_t)bh * 4096) + qt * 64 + wave * 16 + l16) * 64 + quad * 8;
  bf16x8 aq0 = *(const bf16x8*)(qrow);
  bf16x8 aq1 = *(const bf16x8*)(qrow + 32);

  __syncthreads();  // drains vmcnt: K + Vhalf0 resident

  f32x4 s[16];
#pragma unroll
  for (int i = 0; i < 16; i++) s[i] = (f32x4){0.f, 0.f, 0.f, 0.f};
#pragma unroll
  for (int nt = 0; nt < 16; nt++) {
    int krow = nt * 16 + l16;
    const bf16* kb = Ks + krow * 64;
    int sw = (krow & 7) << 3;
    bf16x8 b0 = *(const bf16x8*)(kb + ((quad * 8) ^ sw));
    bf16x8 b1 = *(const bf16x8*)(kb + ((32 + quad * 8) ^ sw));
    s[nt] = MFMA16(aq0, b0, s[nt]);
    s[nt] = MFMA16(aq1, b1, s[nt]);
  }

  const float scale = 0.125f;
#pragma unroll
  for (int r = 0; r < 4; r++) {
    float m = -1e30f;
#pragma unroll
    for (int nt = 0; nt < 16; nt++) m = fmaxf(m, s[nt][r]);
#pragma unroll
    for (int i = 1; i < 16; i <<= 1) m = fmaxf(m, __shfl_xor(m, i, 64));
    float sum = 0.f;
#pragma unroll
    for (int nt = 0; nt < 16; nt++) {
      float e = __expf((s[nt][r] - m) * scale);
      s[nt][r] = e;
      sum += e;
    }
#pragma unroll
    for (int i = 1; i < 16; i <<= 1) sum += __shfl_xor(sum, i, 64);
    float inv = 1.f / sum;
#pragma unroll
    for (int nt = 0; nt < 16; nt++) s[nt][r] *= inv;
  }

  __syncthreads();  // all QK^T reads of Ks done; Ps overwrites it

#pragma unroll
  for (int nt = 0; nt < 16; nt++)
#pragma unroll
    for (int r = 0; r < 4; r++) {
      int prow = wave * 16 + quad * 4 + r;
      Ks[prow * 256 + ((nt * 16 + l16) ^ ((prow & 7) << 3))] = (bf16)s[nt][r];
    }

  int arow = wave * 16 + l16;
  int asw = (arow & 7) << 3;
  const bf16* pb = Ks + arow * 256;
  f32x4 o[4];
#pragma unroll
  for (int i = 0; i < 4; i++) o[i] = (f32x4){0.f, 0.f, 0.f, 0.f};
#pragma unroll
  for (int k0 = 0; k0 < 128; k0 += 32) {
    bf16x8 ap = *(const bf16x8*)(pb + ((k0 + quad * 8) ^ asw));
#pragma unroll
    for (int nt = 0; nt < 4; nt++) {
      int vrow = nt * 16 + l16;
      bf16x8 bv = *(const bf16x8*)(Vs + vrow * 128 + ((k0 + quad * 8) ^ ((vrow & 7) << 3)));
      o[nt] = MFMA16(ap, bv, o[nt]);
    }
  }

  __syncthreads();  // all reads of Vs half0 done
#pragma unroll
  for (int t = 0; t < 4; t++) {
    int chunk = t * 4 + wave;
    gload_lds16(Vbh + (chunk * 4 + (lane >> 4)) * 256 + 128 + (lane & 15) * 8,
                Vs + chunk * 512);
  }
  __syncthreads();  // drain: Vhalf1 resident

#pragma unroll
  for (int k0 = 128; k0 < 256; k0 += 32) {
    bf16x8 ap = *(const bf16x8*)(pb + ((k0 + quad * 8) ^ asw));
    int kl = k0 - 128;
#pragma unroll
    for (int nt = 0; nt < 4; nt++) {
      int vrow = nt * 16 + l16;
      bf16x8 bv = *(const bf16x8*)(Vs + vrow * 128 + ((kl + quad * 8) ^ ((vrow & 7) << 3)));
      o[nt] = MFMA16(ap, bv, o[nt]);
    }
  }

  size_t orow = (size_t)b * 4096 + qt * 64 + wave * 16 + quad * 4;
#pragma unroll
  for (int nt = 0; nt < 4; nt++) {
    int col = h * 64 + nt * 16 + l16;
#pragma unroll
    for (int r = 0; r < 4; r++) O[(orow + r) * 256 + col] = (bf16)o[nt][r];
  }
}

// ---------------- launch ----------------
extern "C" void kernel_launch(void* const* d_in, const int* in_sizes, int n_in,
                              void* d_out, int out_size, void* d_ws, size_t ws_size,
                              hipStream_t stream) {
  (void)in_sizes; (void)n_in; (void)out_size; (void)ws_size;
  const float* x   = (const float*)d_in[0];
  const float* Wq  = (const float*)d_in[3];
  const float* Wkv = (const float*)d_in[4];
  const float* srw = (const float*)d_in[5];
  const float* srb = (const float*)d_in[6];
  const float* lng = (const float*)d_in[7];
  const float* lnb = (const float*)d_in[8];
  const float* Wo  = (const float*)d_in[9];
  const float* bo  = (const float*)d_in[10];
  float* out = (float*)d_out;

  char* ws = (char*)d_ws;
  bf16*  x_bf  = (bf16*)(ws + 0);          // 16,777,216 B
  bf16*  AObuf = (bf16*)(ws + 16777216);   // 16,777,216
  float* convp = (float*)(ws + 33554432);  // 16,777,216 (8 partials; dead after k_ln)
  bf16*  qbuf  = (bf16*)(ws + 33554432);   // aliases convp: Q [32][4096][64]
  bf16*  WqT   = (bf16*)(ws + 50331648);   //    131,072
  bf16*  WkvT  = (bf16*)(ws + 50462720);   //    262,144
  bf16*  WoT   = (bf16*)(ws + 50724864);   //    131,072
  bf16*  srwT  = (bf16*)(ws + 50855936);   //  2,097,152
  bf16*  xln   = (bf16*)(ws + 52953088);   //  1,048,576
  bf16*  kvbuf = (bf16*)(ws + 54001664);   //  2,097,152 (K then V^T, swizzled)

  k_prep<<<10240, 256, 0, stream>>>(x, Wq, Wkv, Wo, srw, x_bf, WqT, WkvT, WoT, srwT);
  // conv (im2col GEMM), split-K 8x512 -> fp32 partials [8][2048][256]
  k_gemm128<1, 4><<<dim3(16, 2, 8), 256, 0, stream>>>(x_bf, srwT, convp, nullptr, 2048, 256, 512);
  // LayerNorm (+partial reduce +sr_b) -> bf16 [2048][256]
  k_ln<<<512, 256, 0, stream>>>(convp, srb, lng, lnb, xln);
  // KV = xln @ Wkv -> K, V^T (swizzled) bf16
  k_gemm<0, 2><<<dim3(32, 8), 256, 0, stream>>>(xln, WkvT, kvbuf, nullptr, 2048, 512, 256);
  // Q = x @ Wq -> [bh][tok][64] (into convp space, now free)
  k_gemm128<0, 5><<<dim3(256, 2), 256, 0, stream>>>(x_bf, WqT, qbuf, nullptr, 32768, 256, 256);
  // attention
  k_attn<<<dim3(32, 64), 256, 0, stream>>>(qbuf, kvbuf, kvbuf + (size_t)32 * 256 * 64, AObuf);
  // out = AO @ Wo + bo -> fp32 d_out
  k_gemm128<0, 3><<<dim3(256, 2), 256, 0, stream>>>(AObuf, WoT, out, bo, 32768, 256, 256);
}

// Round 4
// 176.968 us; speedup vs baseline: 1.3786x; 1.0267x over previous
//
#include <hip/hip_runtime.h>

typedef __bf16 bf16;
typedef bf16 bf16x8 __attribute__((ext_vector_type(8)));
typedef bf16 bf16x4 __attribute__((ext_vector_type(4)));
typedef float f32x4 __attribute__((ext_vector_type(4)));

#define MFMA16(a, b, c) __builtin_amdgcn_mfma_f32_16x16x32_bf16(a, b, c, 0, 0, 0)

// async global->LDS, 16B per lane; lds dest is wave-uniform base (+lane*16 by HW)
__device__ __forceinline__ void gload_lds16(const bf16* g, bf16* l) {
  __builtin_amdgcn_global_load_lds(
      (const __attribute__((address_space(1))) void*)g,
      (__attribute__((address_space(3))) void*)l, 16, 0, 0);
}

// ---------------- merged prep kernel ----------------
// WqT is stored XOR-swizzled (in ^ ((out&7)<<3)) — consumed only by k_attn's
// global_load_lds staging + swizzled ds_read (both-sides-or-neither).
__global__ void k_prep(const float* __restrict__ x, const float* __restrict__ Wq,
                       const float* __restrict__ Wkv, const float* __restrict__ Wo,
                       const float* __restrict__ srw,
                       bf16* __restrict__ x_bf, bf16* __restrict__ WqT,
                       bf16* __restrict__ WkvT, bf16* __restrict__ WoT,
                       bf16* __restrict__ srwT) {
  int bid = blockIdx.x, tid = threadIdx.x;
  if (bid < 8192) {
    int i = (bid * 256 + tid) * 4;
    float4 v = *(const float4*)(x + i);
    bf16x4 o;
    o[0] = (bf16)v.x; o[1] = (bf16)v.y; o[2] = (bf16)v.z; o[3] = (bf16)v.w;
    *(bf16x4*)(x_bf + i) = o;
  } else if (bid < 9216) {
    int id = (bid - 8192) * 256 + tid;  // 0..262143
    if (id < 65536) {                   // WqT (swizzled)
      int c = id >> 8, r = id & 255;    // c = out, r = in
      WqT[c * 256 + (r ^ ((c & 7) << 3))] = (bf16)Wq[r * 256 + c];
    } else if (id < 196608) {           // WkvT
      int l = id - 65536;
      int c = l >> 8, r = l & 255;      // c in 0..511
      WkvT[l] = (bf16)Wkv[r * 512 + c];
    } else {                            // WoT
      int l = id - 196608;
      int c = l >> 8, r = l & 255;
      WoT[l] = (bf16)Wo[r * 256 + c];
    }
  } else {
    int id4 = ((bid - 9216) * 256 + tid) * 4;  // input-linear o*4096+i*16+p
    int o = id4 >> 12, rem = id4 & 4095;
    int i = rem >> 4, p = rem & 15;            // p in {0,4,8,12}
    float4 v = *(const float4*)(srw + id4);
    srwT[(o << 12) + ((p + 0) << 8) + i] = (bf16)v.x;
    srwT[(o << 12) + ((p + 1) << 8) + i] = (bf16)v.y;
    srwT[(o << 12) + ((p + 2) << 8) + i] = (bf16)v.z;
    srwT[(o << 12) + ((p + 3) << 8) + i] = (bf16)v.w;
  }
}

// ---------------- 64x64-tile MFMA GEMM (kept for the small KV GEMM) ----------------
// EMODE 2: KV scatter (XOR-swizzled cols for attn's global_load_lds staging):
//          K  -> [bh][key][d ^ ((key&7)<<3)]
//          V^T-> [bh][d][key ^ ((d&7)<<3)]
template <int AMODE, int EMODE>
__global__ __launch_bounds__(256, 2) void k_gemm(
    const bf16* __restrict__ A, const bf16* __restrict__ Bt,
    void* __restrict__ Cout, const float* __restrict__ bias,
    int M, int N, int K) {
  constexpr int LDT = 72;  // 64 + 8 pad
  __shared__ alignas(16) bf16 As[64 * LDT];
  __shared__ alignas(16) bf16 Bs[64 * LDT];
  int tid = threadIdx.x;
  int m0 = blockIdx.x * 64, n0 = blockIdx.y * 64;
  int kbeg = blockIdx.z * K;
  int wave = tid >> 6, lane = tid & 63;
  int quad = lane >> 4, l16 = lane & 15;

  f32x4 acc[4];
#pragma unroll
  for (int i = 0; i < 4; i++) acc[i] = (f32x4){0.f, 0.f, 0.f, 0.f};

  for (int k0 = kbeg; k0 < kbeg + K; k0 += 64) {
#pragma unroll
    for (int t = 0; t < 2; t++) {
      int c = tid + t * 256;
      int row = c >> 3, c8 = (c & 7) * 8;
      *(bf16x8*)&As[row * LDT + c8] =
          *(const bf16x8*)(A + (size_t)(m0 + row) * K + k0 + c8);
      *(bf16x8*)&Bs[row * LDT + c8] =
          *(const bf16x8*)(Bt + (size_t)(n0 + row) * K + k0 + c8);
    }
    __syncthreads();
#pragma unroll
    for (int kk = 0; kk < 64; kk += 32) {
      bf16x8 af = *(const bf16x8*)&As[(wave * 16 + l16) * LDT + kk + quad * 8];
#pragma unroll
      for (int nt = 0; nt < 4; nt++) {
        bf16x8 bfr = *(const bf16x8*)&Bs[(nt * 16 + l16) * LDT + kk + quad * 8];
        acc[nt] = MFMA16(af, bfr, acc[nt]);
      }
    }
    __syncthreads();
  }

  int rbase = m0 + wave * 16 + quad * 4;
#pragma unroll
  for (int nt = 0; nt < 4; nt++) {
    int col = n0 + nt * 16 + l16;
#pragma unroll
    for (int r = 0; r < 4; r++) {
      float v = acc[nt][r];
      int row = rbase + r;
      if constexpr (EMODE == 2) {
        int b = row >> 8, key = row & 255;
        int isv = col >> 8, c2 = col & 255;
        int hh = c2 >> 6, d = c2 & 63;
        int bh = b * 4 + hh;
        bf16* dst = (bf16*)Cout;
        if (isv == 0)
          dst[(((size_t)bh) * 256 + key) * 64 + (d ^ ((key & 7) << 3))] = (bf16)v;
        else
          dst[32 * 256 * 64 + (((size_t)bh) * 64 + d) * 256 + (key ^ ((d & 7) << 3))] = (bf16)v;
      } else {
        ((float*)Cout)[(size_t)row * N + col] = v + bias[col];
      }
    }
  }
}

// ---------------- 128x128-tile MFMA GEMM (m97 structure) ----------------
template <int AMODE, int EMODE>
__global__ __launch_bounds__(256, 2) void k_gemm128(
    const bf16* __restrict__ A, const bf16* __restrict__ Bt,
    void* __restrict__ Cout, const float* __restrict__ bias,
    int M, int N, int K) {
  __shared__ alignas(16) bf16 As[128 * 64];
  __shared__ alignas(16) bf16 Bs[128 * 64];
  int tid = threadIdx.x;
  int m0 = blockIdx.x * 128, n0 = blockIdx.y * 128;
  int kbeg = blockIdx.z * K;
  int wave = tid >> 6, lane = tid & 63;
  int quad = lane >> 4, l16 = lane & 15;
  int wr = wave >> 1, wc = wave & 1;

  f32x4 acc[4][4];
#pragma unroll
  for (int i = 0; i < 4; i++)
#pragma unroll
    for (int j = 0; j < 4; j++) acc[i][j] = (f32x4){0.f, 0.f, 0.f, 0.f};

  for (int k0 = kbeg; k0 < kbeg + K; k0 += 64) {
#pragma unroll
    for (int t = 0; t < 4; t++) {
      int chunk = wave * 4 + t;            // 0..15, wave-uniform
      int row = chunk * 8 + (lane >> 3);   // 8 rows per chunk
      int c8 = (lane & 7) * 8;             // bf16 offset within row (16B/lane)
      const bf16* asrc;
      if constexpr (AMODE == 0) {
        asrc = A + (size_t)(m0 + row) * K + k0 + c8;
      } else {
        int m = m0 + row;
        int b = m >> 8, tt = m & 255;
        int oh = tt >> 4, ow = tt & 15;
        int p = k0 >> 8;            // patch position (BK=64 never straddles p)
        int kh = p >> 2, kw = p & 3;
        int tok = (oh * 4 + kh) * 64 + ow * 4 + kw;
        asrc = A + ((size_t)(b * 4096 + tok) << 8) + (k0 & 255) + c8;
      }
      gload_lds16(asrc, As + chunk * 512);
      gload_lds16(Bt + (size_t)(n0 + row) * ((AMODE == 1) ? 4096 : K) + k0 + c8,
                  Bs + chunk * 512);
    }
    __syncthreads();
#pragma unroll
    for (int kk = 0; kk < 64; kk += 32) {
      bf16x8 af[4], bfr[4];
#pragma unroll
      for (int mt = 0; mt < 4; mt++)
        af[mt] = *(const bf16x8*)&As[(wr * 64 + mt * 16 + l16) * 64 + kk + quad * 8];
#pragma unroll
      for (int nt = 0; nt < 4; nt++)
        bfr[nt] = *(const bf16x8*)&Bs[(wc * 64 + nt * 16 + l16) * 64 + kk + quad * 8];
#pragma unroll
      for (int mt = 0; mt < 4; mt++)
#pragma unroll
        for (int nt = 0; nt < 4; nt++)
          acc[mt][nt] = MFMA16(af[mt], bfr[nt], acc[mt][nt]);
    }
    __syncthreads();
  }

#pragma unroll
  for (int mt = 0; mt < 4; mt++) {
    int rbase = m0 + wr * 64 + mt * 16 + quad * 4;
#pragma unroll
    for (int nt = 0; nt < 4; nt++) {
      int col = n0 + wc * 64 + nt * 16 + l16;
#pragma unroll
      for (int r = 0; r < 4; r++) {
        float v = acc[mt][nt][r];
        int row = rbase + r;
        if constexpr (EMODE == 3) {
          ((float*)Cout)[(size_t)row * N + col] = v + bias[col];
        } else {  // EMODE 4
          ((float*)Cout)[((size_t)blockIdx.z * M + row) * N + col] = v;
        }
      }
    }
  }
}

// ---------------- LayerNorm (sum of 8 fp32 partials + sr_b -> bf16) ----------------
__global__ void k_ln(const float* __restrict__ part, const float* __restrict__ srb,
                     const float* __restrict__ g, const float* __restrict__ bb,
                     bf16* __restrict__ out) {
  int row = blockIdx.x * 4 + (threadIdx.x >> 6);
  int lane = threadIdx.x & 63;
  size_t off = (size_t)row * 256 + lane * 4;
  float4 v = *(const float4*)&part[off];
#pragma unroll
  for (int z = 1; z < 8; z++) {
    float4 p = *(const float4*)&part[(size_t)z * 2048 * 256 + off];
    v.x += p.x; v.y += p.y; v.z += p.z; v.w += p.w;
  }
  int c = lane * 4;
  v.x += srb[c + 0]; v.y += srb[c + 1]; v.z += srb[c + 2]; v.w += srb[c + 3];
  float s = v.x + v.y + v.z + v.w;
#pragma unroll
  for (int i = 1; i < 64; i <<= 1) s += __shfl_xor(s, i, 64);
  float mu = s * (1.f / 256.f);
  float d0 = v.x - mu, d1 = v.y - mu, d2 = v.z - mu, d3 = v.w - mu;
  float q = d0 * d0 + d1 * d1 + d2 * d2 + d3 * d3;
#pragma unroll
  for (int i = 1; i < 64; i <<= 1) q += __shfl_xor(q, i, 64);
  float rs = rsqrtf(q * (1.f / 256.f) + 1e-5f);
  bf16x4 o;
  o[0] = (bf16)(d0 * rs * g[c + 0] + bb[c + 0]);
  o[1] = (bf16)(d1 * rs * g[c + 1] + bb[c + 1]);
  o[2] = (bf16)(d2 * rs * g[c + 2] + bb[c + 2]);
  o[3] = (bf16)(d3 * rs * g[c + 3] + bb[c + 3]);
  *(bf16x4*)&out[(size_t)row * 256 + c] = o;
}

// ---------------- attention with fused Q-projection ----------------
// grid (32 bh, 64 qtiles), block 256 (4 waves), LDS 48 KiB -> 3 blocks/CU.
// Q-proj: x A-frags straight to regs (8 x dwordx4/lane, cacheline-clean);
// Wq head staged (swizzled storage) into R0, which then holds K, then P.
// Qs uses R2b (wave-private rows) and is recycled as the odd V-quarter buffer.
// V staged in 4 x 8KB quarters, double-buffered R2a/R2b, overlapping compute.
__global__ __launch_bounds__(256, 3) void k_attn(
    const bf16* __restrict__ xbf,  // [B*4096][256]
    const bf16* __restrict__ WqT,  // [256 out][256 in ^ ((out&7)<<3)]
    const bf16* __restrict__ Kg,   // [32][256][64]  cols ^ ((key&7)<<3)
    const bf16* __restrict__ Vg,   // [32][64][256]  cols ^ ((d&7)<<3)
    bf16* __restrict__ O) {        // [B*4096][256]
  int bh = blockIdx.x, qt = blockIdx.y;
  int b = bh >> 2, h = bh & 3;
  int tid = threadIdx.x, wave = tid >> 6, lane = tid & 63;
  int quad = lane >> 4, l16 = lane & 15;

  __shared__ alignas(16) bf16 smem[24576];  // 49152 B
  bf16* R0  = smem;          // [64][256] Wq -> [256][64] K -> [64][256] P
  bf16* R2a = smem + 16384;  // [64][64] V quarter (even)
  bf16* R2b = smem + 20480;  // [64][64] Qs -> V quarter (odd)

  const bf16* Kbh = Kg + ((size_t)bh << 14);
  const bf16* Vbh = Vg + ((size_t)bh << 14);
  const bf16* Wqh = WqT + ((size_t)(h * 64) << 8);

  // ---- stage Wq head (32KB) + V quarter 0 (8KB); x A-frags -> regs ----
#pragma unroll
  for (int t = 0; t < 8; t++) {
    int chunk = t * 4 + wave;
    gload_lds16(Wqh + chunk * 512 + lane * 8, R0 + chunk * 512);
  }
#pragma unroll
  for (int t = 0; t < 2; t++) {
    int chunk = wave * 2 + t;  // wave w covers rows [w*16, w*16+16)
    gload_lds16(Vbh + (chunk * 8 + (lane >> 3)) * 256 + 0 + (lane & 7) * 8,
                R2a + chunk * 512);
  }
  const bf16* xrow =
      xbf + (((size_t)(b * 4096 + qt * 64 + wave * 16 + l16)) << 8) + quad * 8;
  bf16x8 ax[8];
#pragma unroll
  for (int j = 0; j < 8; j++) ax[j] = *(const bf16x8*)(xrow + j * 32);

  __syncthreads();  // B1: Wq + Vq0 resident (ax drained too)

  // ---- Q = x @ Wq_head^T ----
  f32x4 q[4];
#pragma unroll
  for (int i = 0; i < 4; i++) q[i] = (f32x4){0.f, 0.f, 0.f, 0.f};
#pragma unroll
  for (int j = 0; j < 8; j++) {
#pragma unroll
    for (int nt = 0; nt < 4; nt++) {
      int wrow = nt * 16 + l16;
      bf16x8 bw = *(const bf16x8*)&R0[wrow * 256 +
                                      ((j * 32 + quad * 8) ^ ((wrow & 7) << 3))];
      q[nt] = MFMA16(ax[j], bw, q[nt]);
    }
  }
  __syncthreads();  // B2: Wq reads done -> R0 free

  // ---- Qs (swizzled, wave-private rows) -> R2b; stage K -> R0 ----
#pragma unroll
  for (int nt = 0; nt < 4; nt++)
#pragma unroll
    for (int r = 0; r < 4; r++) {
      int qr = wave * 16 + quad * 4 + r;
      R2b[qr * 64 + ((nt * 16 + l16) ^ ((qr & 7) << 3))] = (bf16)q[nt][r];
    }
#pragma unroll
  for (int t = 0; t < 8; t++) {
    int chunk = t * 4 + wave;
    gload_lds16(Kbh + chunk * 512 + lane * 8, R0 + chunk * 512);
  }
  __syncthreads();  // B3: K resident (Qs rows are wave-private anyway)

  int arow = wave * 16 + l16;
  int asw = (arow & 7) << 3;
  bf16x8 aq0 = *(const bf16x8*)&R2b[arow * 64 + ((quad * 8) ^ asw)];
  bf16x8 aq1 = *(const bf16x8*)&R2b[arow * 64 + ((32 + quad * 8) ^ asw)];
  // wave-local: ensure our ds_reads completed before DMA may overwrite R2b.
  // (wave w's Vq1 chunks land exactly on wave w's own Qs rows.)
  asm volatile("s_waitcnt lgkmcnt(0)" ::: "memory");
#pragma unroll
  for (int t = 0; t < 2; t++) {
    int chunk = wave * 2 + t;  // wave w overwrites only its own Qs rows
    gload_lds16(Vbh + (chunk * 8 + (lane >> 3)) * 256 + 64 + (lane & 7) * 8,
                R2b + chunk * 512);
  }

  // ---- S = Q K^T ----
  f32x4 s[16];
#pragma unroll
  for (int i = 0; i < 16; i++) s[i] = (f32x4){0.f, 0.f, 0.f, 0.f};
#pragma unroll
  for (int nt = 0; nt < 16; nt++) {
    int krow = nt * 16 + l16;
    const bf16* kb = R0 + krow * 64;
    int sw = (krow & 7) << 3;
    bf16x8 b0 = *(const bf16x8*)(kb + ((quad * 8) ^ sw));
    bf16x8 b1 = *(const bf16x8*)(kb + ((32 + quad * 8) ^ sw));
    s[nt] = MFMA16(aq0, b0, s[nt]);
    s[nt] = MFMA16(aq1, b1, s[nt]);
  }

  // softmax over 256 keys
  const float scale = 0.125f;
#pragma unroll
  for (int r = 0; r < 4; r++) {
    float m = -1e30f;
#pragma unroll
    for (int nt = 0; nt < 16; nt++) m = fmaxf(m, s[nt][r]);
#pragma unroll
    for (int i = 1; i < 16; i <<= 1) m = fmaxf(m, __shfl_xor(m, i, 64));
    float sum = 0.f;
#pragma unroll
    for (int nt = 0; nt < 16; nt++) {
      float e = __expf((s[nt][r] - m) * scale);
      s[nt][r] = e;
      sum += e;
    }
#pragma unroll
    for (int i = 1; i < 16; i <<= 1) sum += __shfl_xor(sum, i, 64);
    float inv = 1.f / sum;
#pragma unroll
    for (int nt = 0; nt < 16; nt++) s[nt][r] *= inv;
  }

  __syncthreads();  // B4: K reads done -> R0 free; Vq1 resident in R2b

  // ---- P -> R0 swizzled [64][256] (wave-private rows; no barrier after) ----
#pragma unroll
  for (int nt = 0; nt < 16; nt++)
#pragma unroll
    for (int r = 0; r < 4; r++) {
      int prow = wave * 16 + quad * 4 + r;
      R0[prow * 256 + ((nt * 16 + l16) ^ ((prow & 7) << 3))] = (bf16)s[nt][r];
    }

  const bf16* pb = R0 + arow * 256;
  f32x4 o[4];
#pragma unroll
  for (int i = 0; i < 4; i++) o[i] = (f32x4){0.f, 0.f, 0.f, 0.f};

  // ---- O = P V over 4 key-quarters, V double-buffered R2a/R2b ----
#pragma unroll
  for (int cq = 0; cq < 4; cq++) {
    const bf16* Vbuf = (cq & 1) ? R2b : R2a;
#pragma unroll
    for (int k0 = 0; k0 < 64; k0 += 32) {
      bf16x8 ap = *(const bf16x8*)(pb + ((cq * 64 + k0 + quad * 8) ^ asw));
#pragma unroll
      for (int nt = 0; nt < 4; nt++) {
        int vrow = nt * 16 + l16;
        bf16x8 bv = *(const bf16x8*)&Vbuf[vrow * 64 +
                                          ((k0 + quad * 8) ^ ((vrow & 7) << 3))];
        o[nt] = MFMA16(ap, bv, o[nt]);
      }
    }
    if (cq < 3) {
      __syncthreads();  // quarter cq reads done everywhere; quarter cq+1 resident
      if (cq < 2) {     // stage quarter cq+2 into the buffer just freed
        bf16* nb = (cq & 1) ? R2b : R2a;
#pragma unroll
        for (int t = 0; t < 2; t++) {
          int chunk = wave * 2 + t;
          gload_lds16(Vbh + (chunk * 8 + (lane >> 3)) * 256 + (cq + 2) * 64 +
                          (lane & 7) * 8,
                      nb + chunk * 512);
        }
      }
    }
  }

  size_t orow = (size_t)b * 4096 + qt * 64 + wave * 16 + quad * 4;
#pragma unroll
  for (int nt = 0; nt < 4; nt++) {
    int col = h * 64 + nt * 16 + l16;
#pragma unroll
    for (int r = 0; r < 4; r++) O[(orow + r) * 256 + col] = (bf16)o[nt][r];
  }
}

// ---------------- launch ----------------
extern "C" void kernel_launch(void* const* d_in, const int* in_sizes, int n_in,
                              void* d_out, int out_size, void* d_ws, size_t ws_size,
                              hipStream_t stream) {
  (void)in_sizes; (void)n_in; (void)out_size; (void)ws_size;
  const float* x   = (const float*)d_in[0];
  const float* Wq  = (const float*)d_in[3];
  const float* Wkv = (const float*)d_in[4];
  const float* srw = (const float*)d_in[5];
  const float* srb = (const float*)d_in[6];
  const float* lng = (const float*)d_in[7];
  const float* lnb = (const float*)d_in[8];
  const float* Wo  = (const float*)d_in[9];
  const float* bo  = (const float*)d_in[10];
  float* out = (float*)d_out;

  char* ws = (char*)d_ws;
  bf16*  x_bf  = (bf16*)(ws + 0);          // 16,777,216 B
  bf16*  AObuf = (bf16*)(ws + 16777216);   // 16,777,216
  float* convp = (float*)(ws + 33554432);  // 16,777,216 (8 partials)
  bf16*  WqT   = (bf16*)(ws + 50331648);   //    131,072
  bf16*  WkvT  = (bf16*)(ws + 50462720);   //    262,144
  bf16*  WoT   = (bf16*)(ws + 50724864);   //    131,072
  bf16*  srwT  = (bf16*)(ws + 50855936);   //  2,097,152
  bf16*  xln   = (bf16*)(ws + 52953088);   //  1,048,576
  bf16*  kvbuf = (bf16*)(ws + 54001664);   //  2,097,152 (K then V^T, swizzled)

  k_prep<<<10240, 256, 0, stream>>>(x, Wq, Wkv, Wo, srw, x_bf, WqT, WkvT, WoT, srwT);
  // conv (im2col GEMM), split-K 8x512 -> fp32 partials [8][2048][256]
  k_gemm128<1, 4><<<dim3(16, 2, 8), 256, 0, stream>>>(x_bf, srwT, convp, nullptr, 2048, 256, 512);
  // LayerNorm (+partial reduce +sr_b) -> bf16 [2048][256]
  k_ln<<<512, 256, 0, stream>>>(convp, srb, lng, lnb, xln);
  // KV = xln @ Wkv -> K, V^T (swizzled) bf16
  k_gemm<0, 2><<<dim3(32, 8), 256, 0, stream>>>(xln, WkvT, kvbuf, nullptr, 2048, 512, 256);
  // attention (Q-projection fused)
  k_attn<<<dim3(32, 64), 256, 0, stream>>>(x_bf, WqT, kvbuf, kvbuf + (size_t)32 * 256 * 64, AObuf);
  // out = AO @ Wo + bo -> fp32 d_out
  k_gemm128<0, 3><<<dim3(256, 2), 256, 0, stream>>>(AObuf, WoT, out, bo, 32768, 256, 256);
}